// Round 3
// baseline (46.482 us; speedup 1.0000x reference)
//
#include <hip/hip_runtime.h>
#include <hip/hip_bf16.h>
#include <math.h>

#define BB 64
#define HH 80
#define WW 3000
#define RAD 16
#define TW 64             // output columns per strip
#define NLOAD 96          // loaded columns = TW + 2*16 halo
#define XSW 52            // Xs words/row: 48 data + 4 pad (52 % 32 == 20 = 4*odd -> b128 bank-spread)
#define HXS2 228          // Hxp col stride (words): 112 raw rows * 2 + 4 pad (228 % 32 == 4 = 4*odd)
#define NSTRIP 47         // ceil(3000/64)
#define NT 640
#define EPSF 1e-8f

#define XS_WORDS (HH * XSW)              // 4160
#define HXP_OFF  XS_WORDS
#define HXP_WORDS (TW * HXS2)            // 14592
#define ICH_OFF  (XS_WORDS + HXP_WORDS)  // 18752 (byte off 75008, 16B-aligned)
#define TOT_WORDS (ICH_OFF + HH)         // 18832 words = 75328 B -> 2 blocks/CU

typedef float f32x2 __attribute__((ext_vector_type(2)));
typedef float f32x4 __attribute__((ext_vector_type(4)));

__device__ __forceinline__ float bflo(uint32_t w) { return __uint_as_float(w << 16); }
__device__ __forceinline__ float bfhi(uint32_t w) { return __uint_as_float(w & 0xffff0000u); }
__device__ __forceinline__ uint32_t packbf2(float lo, float hi) {
    union { __hip_bfloat162 h2; uint32_t u; } u;
    u.h2 = __hip_bfloat162(__float2bfloat16(lo), __float2bfloat16(hi));
    return u.u;
}

// compile-time-folding element selectors (named registers only — no arrays/unions)
#define E4(V, J) ((J) == 0 ? (V).x : ((J) == 1 ? (V).y : ((J) == 2 ? (V).z : (V).w)))
#define W20(Q) E4((Q) < 4 ? v0 : (Q) < 8 ? v1 : (Q) < 12 ? v2 : (Q) < 16 ? v3 : v4, (Q) & 3)

// phase-3 row selectors: HROW(k) = raw row r0+k (f32x2), TROW(k) = raw row r0+33+k
#define HROW(K) ((K) == 0 ? H0.xy : (K) == 1 ? H0.zw : (K) == 2 ? H1.xy : (K) == 3 ? H1.zw : \
                 (K) == 4 ? H2.xy : (K) == 5 ? H2.zw : (K) == 6 ? H3.xy : H3.zw)
#define TROW(K) ((K) == 0 ? T33 : (K) == 1 ? T45.xy : (K) == 2 ? T45.zw : (K) == 3 ? T67.xy : \
                 (K) == 4 ? T67.zw : (K) == 5 ? T89.xy : T89.zw)

__global__ __launch_bounds__(NT, 5)
void localnorm_kernel(const float* __restrict__ in, float* __restrict__ out) {
    extern __shared__ uint32_t smem[];
    uint32_t* Hxp = smem + HXP_OFF;          // Hxp[col][raw_r] float2 at col*HXS2 + 2*raw_r
    float* inv_ch = (float*)(smem + ICH_OFF);

    const int t     = threadIdx.x;
    const int strip = blockIdx.x % NSTRIP;
    const int b     = blockIdx.x / NSTRIP;
    const int c0    = strip * TW;

    // phase 0: per-row reciprocals + zero Hxp pad rows (raw 0..15 and 96..111) for 64 cols.
    if (t < HH) {
        int lo = max(t - RAD, 0), hi = min(t + RAD, HH - 1);
        inv_ch[t] = 1.0f / (float)(hi - lo + 1);
    }
    {   // 64 cols x 16 uint4 = 1024 zero-fill tasks
        #pragma unroll
        for (int it = 0; it < 2; ++it) {
            const int id = t + it * NT;
            if (it == 0 || id < 1024) {
                const int col = id >> 4;
                const int c8  = id & 15;
                const int off = col * HXS2 + ((c8 < 8) ? (c8 * 4) : (160 + c8 * 4));
                *(uint4*)(Hxp + off) = make_uint4(0u, 0u, 0u, 0u);
            }
        }
    }

    // phase 1: load 96 cols x 80 rows, pack to bf16 pairs. 80 rows x 24 quads = 1920 = 3*640.
    {
        const float* inb = in + (size_t)b * (HH * WW);
        #pragma unroll
        for (int it = 0; it < 3; ++it) {
            const int id  = t + it * NT;
            const int row = id / 24;
            const int q   = id - row * 24;
            const int gc  = c0 - 16 + 4 * q;
            uint2 w2;
            if (gc >= 0 && gc + 4 <= WW) {
                float4 v = *(const float4*)(inb + (size_t)row * WW + gc);
                w2.x = packbf2(v.x, v.y);
                w2.y = packbf2(v.z, v.w);
            } else {
                float p0 = (gc     >= 0 && gc     < WW) ? inb[(size_t)row * WW + gc]     : 0.f;
                float p1 = (gc + 1 >= 0 && gc + 1 < WW) ? inb[(size_t)row * WW + gc + 1] : 0.f;
                float p2 = (gc + 2 >= 0 && gc + 2 < WW) ? inb[(size_t)row * WW + gc + 2] : 0.f;
                float p3 = (gc + 3 >= 0 && gc + 3 < WW) ? inb[(size_t)row * WW + gc + 3] : 0.f;
                w2.x = packbf2(p0, p1);
                w2.y = packbf2(p2, p3);
            }
            *(uint2*)(smem + row * XSW + 2 * q) = w2;
        }
    }
    __syncthreads();

    // phase 2: fused horizontal 33-tap sums of x AND x^2; float2 (Sx,Sxx) output to Hxp.
    // 80 rows x 8 segs of 8 cols = 640 threads; 5 b128 reads each.
    {
        const int row = t % HH;
        const int seg = t / HH;       // 0..7
        const uint32_t* xr = smem + row * XSW + seg * 4;
        uint4 v0 = *(const uint4*)(xr);
        uint4 v1 = *(const uint4*)(xr + 4);
        uint4 v2 = *(const uint4*)(xr + 8);
        uint4 v3 = *(const uint4*)(xr + 12);
        uint4 v4 = *(const uint4*)(xr + 16);
        // initial window: elements e0..e32 (2-way ILP split)
        float l16 = bflo(W20(16));
        float ax = l16,        bx = 0.f;
        float axx = l16 * l16, bxx = 0.f;
        #pragma unroll
        for (int q = 0; q < 16; q += 2) {
            uint32_t wA = W20(q), wB = W20(q + 1);
            float lA = bflo(wA), hA = bfhi(wA);
            float lB = bflo(wB), hB = bfhi(wB);
            ax  += lA + hA;           bx  += lB + hB;
            axx += lA * lA + hA * hA; bxx += lB * lB + hB * hB;
        }
        ax += bx; axx += bxx;
        uint32_t* hw = Hxp + (seg * 8) * HXS2 + 2 * (row + 16);
        #pragma unroll
        for (int k = 0; k < 4; ++k) {
            uint32_t wS = W20(k), wE = W20(k + 16);
            float lS = bflo(wS), hE = bfhi(wE);
            float a1x  = ax - lS + hE;
            float a1xx = axx - lS * lS + hE * hE;
            f32x2 p0; p0.x = ax;  p0.y = axx;
            f32x2 p1; p1.x = a1x; p1.y = a1xx;
            *(f32x2*)(hw + (2 * k) * HXS2)     = p0;
            *(f32x2*)(hw + (2 * k + 1) * HXS2) = p1;
            if (k != 3) {
                float hS = bfhi(wS), lN = bflo(W20(k + 17));
                ax  = a1x - hS + lN;
                axx = a1xx - hS * hS + lN * lN;
            }
        }
    }
    __syncthreads();

    // phase 3: vertical 33-tap packed-f32 sums of (Sx,Sxx) via v_pk_add_f32;
    // mean/var/normalize; direct f32 store. 64 cols x 10 bands of 8 rows = 640 threads.
    {
        const int c    = t & 63;
        const int band = t >> 6;      // 0..9
        const int gc   = c0 + c;
        if (gc < WW) {
            const int r0 = band * 8;
            const uint32_t* hpw = Hxp + c * HXS2 + 2 * r0;   // raw rows r0 .. r0+39 as f32x2
            // head rows r0..r0+7 (live for slides)
            f32x4 H0 = *(const f32x4*)(hpw);
            f32x4 H1 = *(const f32x4*)(hpw + 4);
            f32x4 H2 = *(const f32x4*)(hpw + 8);
            f32x4 H3 = *(const f32x4*)(hpw + 12);
            // middle rows r0+8..r0+31 fold straight into accumulators (short live ranges)
            f32x4 accA = H0 + H2;
            f32x4 accB = H1 + H3;
            #pragma unroll
            for (int m = 0; m < 12; m += 2) {
                accA += *(const f32x4*)(hpw + 16 + 4 * m);
                accB += *(const f32x4*)(hpw + 20 + 4 * m);
            }
            f32x4 acc4 = accA + accB;
            f32x2 a = acc4.xy + acc4.zw;
            a += *(const f32x2*)(hpw + 64);                  // row r0+32
            // tail rows r0+33..r0+39 (live for slides)
            f32x2 T33 = *(const f32x2*)(hpw + 66);
            f32x4 T45 = *(const f32x4*)(hpw + 68);
            f32x4 T67 = *(const f32x4*)(hpw + 72);
            f32x4 T89 = *(const f32x4*)(hpw + 76);

            const float icw = 1.0f / (float)(min(gc + RAD, WW - 1) - max(gc - RAD, 0) + 1);
            f32x4 f4a = *(const f32x4*)(inv_ch + r0);
            f32x4 f4b = *(const f32x4*)(inv_ch + r0 + 4);
            const int  xwoff  = (c + 16) >> 1;
            const bool hiHalf = ((c + 16) & 1) != 0;
            float* outb = out + (size_t)b * (HH * WW);
            #pragma unroll
            for (int k = 0; k < 8; ++k) {
                const int r = r0 + k;
                const float f = E4(k < 4 ? f4a : f4b, k & 3);
                const float ninv = f * icw;
                float mean = a.x * ninv;
                float exx  = a.y * ninv;
                float var  = fmaxf(exx - mean * mean, 0.f);
                float sd   = __builtin_amdgcn_sqrtf(var);
                uint32_t xw = smem[r * XSW + xwoff];
                float xv = hiHalf ? bfhi(xw) : bflo(xw);
                outb[(size_t)r * WW + gc] = (xv - mean) * __builtin_amdgcn_rcpf(sd + EPSF);
                if (k != 7) {
                    a += TROW(k) - HROW(k);   // 2x v_pk_add_f32 (one with neg modifier)
                }
            }
        }
    }
}

extern "C" void kernel_launch(void* const* d_in, const int* in_sizes, int n_in,
                              void* d_out, int out_size, void* d_ws, size_t ws_size,
                              hipStream_t stream) {
    const float* in = (const float*)d_in[0];
    float* out = (float*)d_out;

    const size_t lds_bytes = (size_t)TOT_WORDS * sizeof(uint32_t);  // 75328
    static bool attr_set = false;
    if (!attr_set) {
        (void)hipFuncSetAttribute((const void*)localnorm_kernel,
                                  hipFuncAttributeMaxDynamicSharedMemorySize,
                                  (int)lds_bytes);
        attr_set = true;
    }

    dim3 grid(BB * NSTRIP);
    dim3 block(NT);
    localnorm_kernel<<<grid, block, lds_bytes, stream>>>(in, out);
}